// Round 1
// baseline (629.738 us; speedup 1.0000x reference)
//
#include <hip/hip_runtime.h>
#include <stdint.h>

typedef __attribute__((ext_vector_type(8))) short bf16x8;
typedef __attribute__((ext_vector_type(4))) float f32x4;
typedef unsigned long long ull;

typedef uint4 uint4_a __attribute__((may_alias));
typedef ull ull_a __attribute__((may_alias));
typedef bf16x8 bf16x8_a __attribute__((may_alias));

#define LGKM0() __builtin_amdgcn_s_waitcnt(0xc07f)
#define MFMA16(a, b, c) __builtin_amdgcn_mfma_f32_16x16x32_bf16((a), (b), (c), 0, 0, 0)

__device__ __forceinline__ unsigned f2bf(float x) {
    unsigned u = __float_as_uint(x);
    return (u + 0x7fffu + ((u >> 16) & 1u)) >> 16;
}
__device__ __forceinline__ float bf2f(short s) {
    return __uint_as_float(((unsigned)(unsigned short)s) << 16);
}
__device__ __forceinline__ ull pack4(f32x4 v) {
    return (ull)f2bf(v.x) | ((ull)f2bf(v.y) << 16) | ((ull)f2bf(v.z) << 32) | ((ull)f2bf(v.w) << 48);
}

// ---------------- prepass: weight bf16 convert + h_task + w_src/w_dst + ew ----
__global__ void gat_prep(const float* __restrict__ te, const float* __restrict__ W_in,
                         const float* __restrict__ b_in, const float* __restrict__ W_heads,
                         const float* __restrict__ a_heads, const float* __restrict__ om_i,
                         const float* __restrict__ om_c, const int* __restrict__ adj,
                         const int* __restrict__ et, const float* __restrict__ out_W,
                         unsigned short* __restrict__ wsW1, unsigned short* __restrict__ wsW2,
                         unsigned short* __restrict__ wsWsd, float* __restrict__ wsHt,
                         float* __restrict__ wsEw, float* __restrict__ eout) {
    const int gid = blockIdx.x, tid = threadIdx.x;
    if (gid < 1024) {  // elementwise f32->bf16 of W_heads (131072) and out_W (131072)
        int idx = gid * 256 + tid;
        if (idx < 131072) wsW1[idx] = (unsigned short)f2bf(W_heads[idx]);
        else wsW2[idx - 131072] = (unsigned short)f2bf(out_W[idx - 131072]);
    } else if (gid < 1028) {  // h_task[8][128] fp32
        int idx = (gid - 1024) * 256 + tid;  // [0,1024)
        int n = idx >> 7, o = idx & 127;
        float s = b_in[o];
        for (int f = 0; f < 64; ++f) s += te[n * 64 + f] * W_in[o * 64 + f];
        wsHt[idx] = s;
    } else if (gid < 1044) {  // Wsd[l][16][128]: w_src/w_dst = W1^T a, rows p>=8 zero
        int idx = (gid - 1028) * 256 + tid;  // [0,4096)
        int l = idx >> 11, p = (idx >> 7) & 15, f = idx & 127;
        float s = 0.f;
        if (p < 8) {
            int hh = p >> 1, ss = p & 1;
            const float* a = a_heads + (l * 4 + hh) * 256 + ss * 128;
            const float* Wb = W_heads + (l * 4 + hh) * 16384;
            for (int g = 0; g < 128; ++g) s += a[g] * Wb[g * 128 + f];
        }
        wsWsd[idx] = (unsigned short)f2bf(s);
    } else {  // ew (includes adjacency zeros) -> ws and output tail
        if (tid < 64) {
            float v = 0.f;
            if (adj[tid]) {
                int t = et[tid];
                v = (t == 1) ? om_i[0] : ((t == 2) ? om_c[0] : 1.0f);
            }
            wsEw[tid] = v;
            eout[tid] = v;
        }
    }
}

// ---------------- staging prefetch ------------------------------------------
__device__ __forceinline__ void load_chunk(int chunk, int tid,
                                           const unsigned short* __restrict__ wsW1,
                                           const unsigned short* __restrict__ wsW2, uint4* pf) {
    const int l = chunk >> 3, h = (chunk >> 1) & 3;
    const int r = tid >> 1, fh = (tid & 1) << 6;
    const unsigned short* src = (chunk & 1) ? (wsW2 + ((l << 7) + r) * 512 + (h << 7) + fh)
                                            : (wsW1 + (((l << 2) + h) * 128 + r) * 128 + fh);
#pragma unroll
    for (int k = 0; k < 8; ++k) pf[k] = *(const uint4_a*)(src + 8 * k);
}

// ---------------- fused GAT kernel ------------------------------------------
// 256 threads = 4 waves; wave owns 64 rows = 8 batch elements; block = 256 rows.
__global__ __launch_bounds__(256, 1) void gat_main(
    const float* __restrict__ shared_emb, const float* __restrict__ out_b,
    const float* __restrict__ ln_s, const float* __restrict__ ln_b,
    const unsigned short* __restrict__ wsW1, const unsigned short* __restrict__ wsW2,
    const unsigned short* __restrict__ wsWsd, const float* __restrict__ wsHt,
    const float* __restrict__ wsEw, float* __restrict__ out) {
    __shared__ __align__(16) unsigned short sW[2][128 * 136];  // staged W chunk (dbl buf)
    __shared__ __align__(16) unsigned short sScr[4][9216];     // per-wave whT / hp / gL scratch
    __shared__ __align__(16) float sE[4][64][8];               // per-wave ei/ej
    __shared__ __align__(16) unsigned short sAtt[4][64][8];    // per-wave att row coefs (bf16)

    const int tid = threadIdx.x;
    const int w = tid >> 6, lane = tid & 63, q = lane >> 4, c = lane & 15;
    const long wrow0 = (long)blockIdx.x * 256 + (long)w * 64;

    // edge-weight row for this lane's att task (task = lane&7), constant all layers
    float ewr[8];
#pragma unroll
    for (int m = 0; m < 8; ++m) ewr[m] = wsEw[(lane & 7) * 8 + m];

    // X fragments in registers (A-layout): row = 16*mt + c, f = 32*kk + 8*q + j
    bf16x8 xf[4][4];
#pragma unroll
    for (int mt = 0; mt < 4; ++mt) {
        const long row = wrow0 + 16 * mt + c;
        const size_t b = (size_t)(row >> 3);
        const int t = (int)(row & 7);
#pragma unroll
        for (int kk = 0; kk < 4; ++kk) {
            const int f0 = 32 * kk + 8 * q;
            const float4 s0 = *(const float4*)(shared_emb + b * 128 + f0);
            const float4 s1 = *(const float4*)(shared_emb + b * 128 + f0 + 4);
            const float4 h0 = *(const float4*)(wsHt + t * 128 + f0);
            const float4 h1 = *(const float4*)(wsHt + t * 128 + f0 + 4);
            float v[8] = {s0.x + h0.x, s0.y + h0.y, s0.z + h0.z, s0.w + h0.w,
                          s1.x + h1.x, s1.y + h1.y, s1.z + h1.z, s1.w + h1.w};
            bf16x8 r;
#pragma unroll
            for (int j = 0; j < 8; ++j) r[j] = (short)f2bf(v[j]);
            xf[mt][kk] = r;
        }
    }

    f32x4 gacc[8][4];  // goutT accumulators [ot][nt], persist across the 4 heads
    uint4 pf[8];
    load_chunk(0, tid, wsW1, wsW2, pf);

    for (int chunk = 0; chunk < 16; ++chunk) {
        const int l = chunk >> 3, h = (chunk >> 1) & 3, isW2 = chunk & 1;
        {  // commit staged chunk to LDS
            const int g = tid >> 1, fh = (tid & 1) << 6;
            unsigned short* dst = &sW[chunk & 1][g * 136 + fh];
#pragma unroll
            for (int k = 0; k < 8; ++k) *(uint4_a*)(dst + 8 * k) = pf[k];
        }
        if (chunk < 15) load_chunk(chunk + 1, tid, wsW1, wsW2, pf);
        __syncthreads();

        if (!isW2) {
            if (h == 0) {  // layer start: zero gacc, E-GEMM (ei/ej for all heads)
                const f32x4 z4 = {0.f, 0.f, 0.f, 0.f};
#pragma unroll
                for (int ot = 0; ot < 8; ++ot)
#pragma unroll
                    for (int nt = 0; nt < 4; ++nt) gacc[ot][nt] = z4;
                f32x4 e[4] = {z4, z4, z4, z4};
#pragma unroll
                for (int kk = 0; kk < 4; ++kk) {
                    bf16x8 bw = *(const bf16x8_a*)(wsWsd + ((l << 4) + c) * 128 + 32 * kk + 8 * q);
#pragma unroll
                    for (int mt = 0; mt < 4; ++mt) e[mt] = MFMA16(xf[mt][kk], bw, e[mt]);
                }
                if (c < 8) {
#pragma unroll
                    for (int mt = 0; mt < 4; ++mt)
#pragma unroll
                        for (int r = 0; r < 4; ++r) sE[w][16 * mt + 4 * q + r][c] = e[mt][r];
                }
                LGKM0();
            }
            {  // attention coefficients for head h: one row per lane
                const int r = lane, eb = r & 56;
                const float ei = sE[w][r][2 * h];
                float lgt[8];
#pragma unroll
                for (int m = 0; m < 8; ++m) {
                    float s = ei + sE[w][eb + m][2 * h + 1];
                    s = s > 0.f ? s : 0.2f * s;  // leaky_relu 0.2
                    lgt[m] = s * ewr[m];         // masked entries -> exactly 0 (matches ref)
                }
                float mx = lgt[0];
#pragma unroll
                for (int m = 1; m < 8; ++m) mx = fmaxf(mx, lgt[m]);
                float p[8], sum = 0.f;
#pragma unroll
                for (int m = 0; m < 8; ++m) {
                    p[m] = __expf(lgt[m] - mx);
                    sum += p[m];
                }
                const float inv = 1.0f / sum;
                uint4 av;
                av.x = f2bf(p[0] * inv) | (f2bf(p[1] * inv) << 16);
                av.y = f2bf(p[2] * inv) | (f2bf(p[3] * inv) << 16);
                av.z = f2bf(p[4] * inv) | (f2bf(p[5] * inv) << 16);
                av.w = f2bf(p[6] * inv) | (f2bf(p[7] * inv) << 16);
                *(uint4_a*)&sAtt[w][r][0] = av;
            }
            // GEMM1: Wh[row][g] = X . W1^T
            f32x4 acc[32];
            {
                const f32x4 z4 = {0.f, 0.f, 0.f, 0.f};
#pragma unroll
                for (int i = 0; i < 32; ++i) acc[i] = z4;
            }
#pragma unroll
            for (int kk = 0; kk < 4; ++kk)
#pragma unroll
                for (int gt = 0; gt < 8; ++gt) {
                    bf16x8 bw = *(const bf16x8_a*)&sW[chunk & 1][(16 * gt + c) * 136 + 32 * kk + 8 * q];
#pragma unroll
                    for (int mt = 0; mt < 4; ++mt)
                        acc[mt * 8 + gt] = MFMA16(xf[mt][kk], bw, acc[mt * 8 + gt]);
                }
            LGKM0();  // prior-head hp reads drained before overwriting scratch
            // whT store: sScr[g][row] (bf16), packed b64 along rows
#pragma unroll
            for (int gt = 0; gt < 8; ++gt)
#pragma unroll
                for (int mt = 0; mt < 4; ++mt)
                    *(ull_a*)&sScr[w][(16 * gt + c) * 72 + 16 * mt + 4 * q] = pack4(acc[mt * 8 + gt]);
            LGKM0();
            // mix-MFMA: hpT[cd][n] = sum_k WhT[cd][k] * attT[k][n] (block-diag att)
            bf16x8 bat[4];
#pragma unroll
            for (int nt = 0; nt < 4; ++nt) {
                const int kk = nt >> 1;
                const int n = 16 * nt + c;
                bf16x8 zb;
#pragma unroll
                for (int j = 0; j < 8; ++j) zb[j] = 0;
                bat[nt] = ((n >> 3) == 4 * kk + q) ? *(const bf16x8_a*)&sAtt[w][n][0] : zb;
            }
            {
                const f32x4 z4 = {0.f, 0.f, 0.f, 0.f};
#pragma unroll
                for (int i = 0; i < 32; ++i) acc[i] = z4;
            }
#pragma unroll
            for (int ct = 0; ct < 8; ++ct) {
                bf16x8 a0 = *(const bf16x8_a*)&sScr[w][(16 * ct + c) * 72 + 8 * q];
                bf16x8 a1 = *(const bf16x8_a*)&sScr[w][(16 * ct + c) * 72 + 32 + 8 * q];
#pragma unroll
                for (int nt = 0; nt < 4; ++nt)
                    acc[ct * 4 + nt] = MFMA16((nt >> 1) ? a1 : a0, bat[nt], acc[ct * 4 + nt]);
            }
            LGKM0();  // whT reads drained before hp overwrites scratch
            // elu + hp store: sScr[row][cd] (bf16, pitch 136)
#pragma unroll
            for (int ct = 0; ct < 8; ++ct)
#pragma unroll
                for (int nt = 0; nt < 4; ++nt) {
                    f32x4 v = acc[ct * 4 + nt];
#pragma unroll
                    for (int j = 0; j < 4; ++j) {
                        float x = v[j];
                        v[j] = x > 0.f ? x : (__expf(x) - 1.f);
                    }
                    *(ull_a*)&sScr[w][(16 * nt + c) * 136 + 16 * ct + 4 * q] = pack4(v);
                }
            LGKM0();
        } else {
            // GEMM2 (transposed out): goutT[o][n] += W2_h . hp^T
#pragma unroll
            for (int kk = 0; kk < 4; ++kk) {
                bf16x8 bh[4];
#pragma unroll
                for (int nt = 0; nt < 4; ++nt)
                    bh[nt] = *(const bf16x8_a*)&sScr[w][(16 * nt + c) * 136 + 32 * kk + 8 * q];
#pragma unroll
                for (int ot = 0; ot < 8; ++ot) {
                    bf16x8 aw = *(const bf16x8_a*)&sW[chunk & 1][(16 * ot + c) * 136 + 32 * kk + 8 * q];
#pragma unroll
                    for (int nt = 0; nt < 4; ++nt) gacc[ot][nt] = MFMA16(aw, bh[nt], gacc[ot][nt]);
                }
            }
            if (h == 3) {  // epilogue: residual + bias + layernorm (per layer)
                LGKM0();
#pragma unroll
                for (int ot = 0; ot < 8; ++ot)
#pragma unroll
                    for (int nt = 0; nt < 4; ++nt)
                        *(ull_a*)&sScr[w][(16 * nt + c) * 136 + 16 * ot + 4 * q] = pack4(gacc[ot][nt]);
                LGKM0();
                const float* ob = out_b + l * 128;
                float sum[4] = {0.f, 0.f, 0.f, 0.f}, ssq[4] = {0.f, 0.f, 0.f, 0.f};
#pragma unroll
                for (int mt = 0; mt < 4; ++mt)
#pragma unroll
                    for (int kk = 0; kk < 4; ++kk) {
                        bf16x8 g8 = *(const bf16x8_a*)&sScr[w][(16 * mt + c) * 136 + 32 * kk + 8 * q];
                        bf16x8 x8 = xf[mt][kk];
                        const int f0 = 32 * kk + 8 * q;
#pragma unroll
                        for (int j = 0; j < 8; ++j) {
                            float x = bf2f(g8[j]) + bf2f(x8[j]) + ob[f0 + j];
                            sum[mt] += x;
                            ssq[mt] += x * x;
                        }
                    }
                float mu[4], rs[4];
#pragma unroll
                for (int mt = 0; mt < 4; ++mt) {
                    sum[mt] += __shfl_xor(sum[mt], 16);
                    sum[mt] += __shfl_xor(sum[mt], 32);
                    ssq[mt] += __shfl_xor(ssq[mt], 16);
                    ssq[mt] += __shfl_xor(ssq[mt], 32);
                    mu[mt] = sum[mt] * (1.0f / 128.0f);
                    float var = ssq[mt] * (1.0f / 128.0f) - mu[mt] * mu[mt];
                    rs[mt] = rsqrtf(var + 1e-5f);
                }
                const float* lsc = ln_s + l * 128;
                const float* lbi = ln_b + l * 128;
#pragma unroll
                for (int mt = 0; mt < 4; ++mt) {
                    const long row = wrow0 + 16 * mt + c;
#pragma unroll
                    for (int kk = 0; kk < 4; ++kk) {
                        bf16x8 g8 = *(const bf16x8_a*)&sScr[w][(16 * mt + c) * 136 + 32 * kk + 8 * q];
                        bf16x8 x8 = xf[mt][kk];
                        const int f0 = 32 * kk + 8 * q;
                        float y[8];
#pragma unroll
                        for (int j = 0; j < 8; ++j) {
                            float x = bf2f(g8[j]) + bf2f(x8[j]) + ob[f0 + j];
                            y[j] = (x - mu[mt]) * rs[mt] * lsc[f0 + j] + lbi[f0 + j];
                        }
                        if (l == 0) {
                            bf16x8 r;
#pragma unroll
                            for (int j = 0; j < 8; ++j) r[j] = (short)f2bf(y[j]);
                            xf[mt][kk] = r;
                        } else {
                            float4 o0 = {y[0], y[1], y[2], y[3]};
                            float4 o1 = {y[4], y[5], y[6], y[7]};
                            *(float4*)(out + (size_t)row * 128 + f0) = o0;
                            *(float4*)(out + (size_t)row * 128 + f0 + 4) = o1;
                        }
                    }
                }
            }
        }
    }
}

extern "C" void kernel_launch(void* const* d_in, const int* in_sizes, int n_in, void* d_out,
                              int out_size, void* d_ws, size_t ws_size, hipStream_t stream) {
    const float* shared_emb = (const float*)d_in[0];
    const float* te = (const float*)d_in[1];
    const float* W_in = (const float*)d_in[2];
    const float* b_in = (const float*)d_in[3];
    const float* W_heads = (const float*)d_in[4];
    const float* a_heads = (const float*)d_in[5];
    const float* out_W = (const float*)d_in[6];
    const float* out_b = (const float*)d_in[7];
    const float* ln_s = (const float*)d_in[8];
    const float* ln_b = (const float*)d_in[9];
    const float* om_i = (const float*)d_in[10];
    const float* om_c = (const float*)d_in[11];
    const int* adj = (const int*)d_in[12];
    const int* et = (const int*)d_in[13];
    float* out = (float*)d_out;

    unsigned short* wsW1 = (unsigned short*)d_ws;          // [2][4][128][128] bf16
    unsigned short* wsW2 = wsW1 + 131072;                  // [2][128][512] bf16
    unsigned short* wsWsd = wsW2 + 131072;                 // [2][16][128] bf16
    float* wsHt = (float*)((char*)d_ws + 532480);          // [8][128] f32
    float* wsEw = wsHt + 1024;                             // [64] f32
    // total ws need: 536,832 bytes

    float* eout = out + (out_size - 64);  // ew output tail

    gat_prep<<<1045, 256, 0, stream>>>(te, W_in, b_in, W_heads, a_heads, om_i, om_c, adj, et,
                                       out_W, wsW1, wsW2, wsWsd, wsHt, wsEw, eout);

    const int B = in_sizes[0] / 128;       // 16384
    const int grid = (B * 8) / 256;        // 512 blocks, 256 rows each
    gat_main<<<grid, 256, 0, stream>>>(shared_emb, out_b, ln_s, ln_b, wsW1, wsW2, wsWsd, wsHt,
                                       wsEw, out);
}

// Round 2
// 360.755 us; speedup vs baseline: 1.7456x; 1.7456x over previous
//
#include <hip/hip_runtime.h>
#include <stdint.h>

typedef __attribute__((ext_vector_type(8))) short bf16x8;
typedef __attribute__((ext_vector_type(4))) float f32x4;
typedef unsigned long long ull;

typedef uint4 uint4_a __attribute__((may_alias));
typedef ull ull_a __attribute__((may_alias));
typedef bf16x8 bf16x8_a __attribute__((may_alias));

#define LGKM0() __builtin_amdgcn_s_waitcnt(0xc07f)
#define MFMA16(a, b, c) __builtin_amdgcn_mfma_f32_16x16x32_bf16((a), (b), (c), 0, 0, 0)

__device__ __forceinline__ unsigned f2bf(float x) {
    unsigned u = __float_as_uint(x);
    return (u + 0x7fffu + ((u >> 16) & 1u)) >> 16;
}
__device__ __forceinline__ float bf2f(short s) {
    return __uint_as_float(((unsigned)(unsigned short)s) << 16);
}
__device__ __forceinline__ ull pack4(f32x4 v) {
    return (ull)f2bf(v.x) | ((ull)f2bf(v.y) << 16) | ((ull)f2bf(v.z) << 32) | ((ull)f2bf(v.w) << 48);
}

// ---------------- prepass: weight bf16 convert + h_task + w_src/w_dst + ew ----
__global__ void gat_prep(const float* __restrict__ te, const float* __restrict__ W_in,
                         const float* __restrict__ b_in, const float* __restrict__ W_heads,
                         const float* __restrict__ a_heads, const float* __restrict__ om_i,
                         const float* __restrict__ om_c, const int* __restrict__ adj,
                         const int* __restrict__ et, const float* __restrict__ out_W,
                         unsigned short* __restrict__ wsW1, unsigned short* __restrict__ wsW2,
                         unsigned short* __restrict__ wsWsd, float* __restrict__ wsHt,
                         float* __restrict__ wsEw, float* __restrict__ eout) {
    const int gid = blockIdx.x, tid = threadIdx.x;
    if (gid < 1024) {  // elementwise f32->bf16 of W_heads (131072) and out_W (131072)
        int idx = gid * 256 + tid;
        if (idx < 131072) wsW1[idx] = (unsigned short)f2bf(W_heads[idx]);
        else wsW2[idx - 131072] = (unsigned short)f2bf(out_W[idx - 131072]);
    } else if (gid < 1028) {  // h_task[8][128] fp32
        int idx = (gid - 1024) * 256 + tid;  // [0,1024)
        int n = idx >> 7, o = idx & 127;
        float s = b_in[o];
        for (int f = 0; f < 64; ++f) s += te[n * 64 + f] * W_in[o * 64 + f];
        wsHt[idx] = s;
    } else if (gid < 1044) {  // Wsd[l][16][128]: w_src/w_dst = W1^T a, rows p>=8 zero
        int idx = (gid - 1028) * 256 + tid;  // [0,4096)
        int l = idx >> 11, p = (idx >> 7) & 15, f = idx & 127;
        float s = 0.f;
        if (p < 8) {
            int hh = p >> 1, ss = p & 1;
            const float* a = a_heads + (l * 4 + hh) * 256 + ss * 128;
            const float* Wb = W_heads + (l * 4 + hh) * 16384;
            for (int g = 0; g < 128; ++g) s += a[g] * Wb[g * 128 + f];
        }
        wsWsd[idx] = (unsigned short)f2bf(s);
    } else {  // ew (includes adjacency zeros) -> ws and output tail
        if (tid < 64) {
            float v = 0.f;
            if (adj[tid]) {
                int t = et[tid];
                v = (t == 1) ? om_i[0] : ((t == 2) ? om_c[0] : 1.0f);
            }
            wsEw[tid] = v;
            eout[tid] = v;
        }
    }
}

// ---------------- staging prefetch (512 threads, 64 B/thread) ----------------
__device__ __forceinline__ void load_chunk(int chunk, int tid,
                                           const unsigned short* __restrict__ wsW1,
                                           const unsigned short* __restrict__ wsW2, uint4* pf) {
    const int l = chunk >> 3, h = (chunk >> 1) & 3;
    const int r = tid >> 2, part = tid & 3;
    const unsigned short* src = (chunk & 1) ? (wsW2 + ((l << 7) + r) * 512 + (h << 7) + part * 32)
                                            : (wsW1 + (((l << 2) + h) * 128 + r) * 128 + part * 32);
#pragma unroll
    for (int k = 0; k < 4; ++k) pf[k] = *(const uint4_a*)(src + 8 * k);
}

// ---------------- fused GAT kernel ------------------------------------------
// 512 threads = 8 waves; wave owns 32 rows = 4 batch elements; block = 256 rows.
__global__ __launch_bounds__(512, 1) void gat_main(
    const float* __restrict__ shared_emb, const float* __restrict__ out_b,
    const float* __restrict__ ln_s, const float* __restrict__ ln_b,
    const unsigned short* __restrict__ wsW1, const unsigned short* __restrict__ wsW2,
    const unsigned short* __restrict__ wsWsd, const float* __restrict__ wsHt,
    const float* __restrict__ wsEw, float* __restrict__ out) {
    __shared__ __align__(16) unsigned short sW[128 * 136];   // staged W chunk (single buf)
    __shared__ __align__(16) unsigned short sScr[8][5120];   // per-wave whT(128x40) / hp(32x136)
    __shared__ __align__(16) float sE[8][32][8];             // per-wave ei/ej
    __shared__ __align__(16) unsigned short sAtt[8][32][8];  // per-wave att row coefs (bf16)

    const int tid = threadIdx.x;
    const int w = tid >> 6, lane = tid & 63, q = lane >> 4, c = lane & 15;
    const long wrow0 = (long)blockIdx.x * 256 + (long)w * 32;

    // edge-weight row for this lane's att task (task = lane&7), constant all layers
    float ewr[8];
#pragma unroll
    for (int m = 0; m < 8; ++m) ewr[m] = wsEw[(lane & 7) * 8 + m];

    // X fragments in registers (A-layout): row = 16*mt + c, f = 32*kk + 8*q + j
    bf16x8 xf[2][4];
#pragma unroll
    for (int mt = 0; mt < 2; ++mt) {
        const long row = wrow0 + 16 * mt + c;
        const size_t b = (size_t)(row >> 3);
        const int t = (int)(row & 7);
#pragma unroll
        for (int kk = 0; kk < 4; ++kk) {
            const int f0 = 32 * kk + 8 * q;
            const float4 s0 = *(const float4*)(shared_emb + b * 128 + f0);
            const float4 s1 = *(const float4*)(shared_emb + b * 128 + f0 + 4);
            const float4 h0 = *(const float4*)(wsHt + t * 128 + f0);
            const float4 h1 = *(const float4*)(wsHt + t * 128 + f0 + 4);
            float v[8] = {s0.x + h0.x, s0.y + h0.y, s0.z + h0.z, s0.w + h0.w,
                          s1.x + h1.x, s1.y + h1.y, s1.z + h1.z, s1.w + h1.w};
            bf16x8 r;
#pragma unroll
            for (int j = 0; j < 8; ++j) r[j] = (short)f2bf(v[j]);
            xf[mt][kk] = r;
        }
    }

    f32x4 gacc[8][2];  // goutT accumulators [ot][nt], persist across the 4 heads
    uint4 pf[4];
    load_chunk(0, tid, wsW1, wsW2, pf);

    for (int chunk = 0; chunk < 16; ++chunk) {
        const int l = chunk >> 3, h = (chunk >> 1) & 3, isW2 = chunk & 1;
        {  // commit staged chunk to LDS (single buffer, fenced by both barriers)
            const int r = tid >> 2, part = tid & 3;
            unsigned short* dst = &sW[r * 136 + part * 32];
#pragma unroll
            for (int k = 0; k < 4; ++k) *(uint4_a*)(dst + 8 * k) = pf[k];
        }
        if (chunk < 15) load_chunk(chunk + 1, tid, wsW1, wsW2, pf);
        __syncthreads();

        if (!isW2) {
            if (h == 0) {  // layer start: zero gacc, E-GEMM (ei/ej for all heads)
                const f32x4 z4 = {0.f, 0.f, 0.f, 0.f};
#pragma unroll
                for (int ot = 0; ot < 8; ++ot)
#pragma unroll
                    for (int nt = 0; nt < 2; ++nt) gacc[ot][nt] = z4;
                f32x4 e[2] = {z4, z4};
#pragma unroll
                for (int kk = 0; kk < 4; ++kk) {
                    bf16x8 bw = *(const bf16x8_a*)(wsWsd + ((l << 4) + c) * 128 + 32 * kk + 8 * q);
#pragma unroll
                    for (int mt = 0; mt < 2; ++mt) e[mt] = MFMA16(xf[mt][kk], bw, e[mt]);
                }
                if (c < 8) {
#pragma unroll
                    for (int mt = 0; mt < 2; ++mt)
#pragma unroll
                        for (int r = 0; r < 4; ++r) sE[w][16 * mt + 4 * q + r][c] = e[mt][r];
                }
                LGKM0();
            }
            if (lane < 32) {  // attention coefficients for head h: one row per lane
                const int r = lane, eb = r & 24;
                const float ei = sE[w][r][2 * h];
                float lgt[8];
#pragma unroll
                for (int m = 0; m < 8; ++m) {
                    float s = ei + sE[w][eb + m][2 * h + 1];
                    s = s > 0.f ? s : 0.2f * s;  // leaky_relu 0.2
                    lgt[m] = s * ewr[m];         // masked entries -> exactly 0 (matches ref)
                }
                float mx = lgt[0];
#pragma unroll
                for (int m = 1; m < 8; ++m) mx = fmaxf(mx, lgt[m]);
                float p[8], sum = 0.f;
#pragma unroll
                for (int m = 0; m < 8; ++m) {
                    p[m] = __expf(lgt[m] - mx);
                    sum += p[m];
                }
                const float inv = 1.0f / sum;
                uint4 av;
                av.x = f2bf(p[0] * inv) | (f2bf(p[1] * inv) << 16);
                av.y = f2bf(p[2] * inv) | (f2bf(p[3] * inv) << 16);
                av.z = f2bf(p[4] * inv) | (f2bf(p[5] * inv) << 16);
                av.w = f2bf(p[6] * inv) | (f2bf(p[7] * inv) << 16);
                *(uint4_a*)&sAtt[w][r][0] = av;
            }
            // GEMM1: Wh[row][g] = X . W1^T
            f32x4 acc[16];
            {
                const f32x4 z4 = {0.f, 0.f, 0.f, 0.f};
#pragma unroll
                for (int i = 0; i < 16; ++i) acc[i] = z4;
            }
#pragma unroll
            for (int kk = 0; kk < 4; ++kk)
#pragma unroll
                for (int gt = 0; gt < 8; ++gt) {
                    bf16x8 bw = *(const bf16x8_a*)&sW[(16 * gt + c) * 136 + 32 * kk + 8 * q];
#pragma unroll
                    for (int mt = 0; mt < 2; ++mt)
                        acc[mt * 8 + gt] = MFMA16(xf[mt][kk], bw, acc[mt * 8 + gt]);
                }
            LGKM0();  // prior-phase sScr reads drained before overwriting scratch
            // whT store: sScr[g][row] (bf16, pitch 40), packed b64 along rows
#pragma unroll
            for (int gt = 0; gt < 8; ++gt)
#pragma unroll
                for (int mt = 0; mt < 2; ++mt)
                    *(ull_a*)&sScr[w][(16 * gt + c) * 40 + 16 * mt + 4 * q] = pack4(acc[mt * 8 + gt]);
            LGKM0();
            // mix-MFMA: hpT[cd][n] = sum_k WhT[cd][k] * attT[k][n] (block-diag att, K=32)
            bf16x8 bat[2];
#pragma unroll
            for (int nt = 0; nt < 2; ++nt) {
                const int n = 16 * nt + c;
                bf16x8 zb;
#pragma unroll
                for (int j = 0; j < 8; ++j) zb[j] = 0;
                bat[nt] = (q == 2 * nt + (c >> 3)) ? *(const bf16x8_a*)&sAtt[w][n][0] : zb;
            }
            {
                const f32x4 z4 = {0.f, 0.f, 0.f, 0.f};
#pragma unroll
                for (int i = 0; i < 16; ++i) acc[i] = z4;
            }
#pragma unroll
            for (int ct = 0; ct < 8; ++ct) {
                bf16x8 a0 = *(const bf16x8_a*)&sScr[w][(16 * ct + c) * 40 + 8 * q];
#pragma unroll
                for (int nt = 0; nt < 2; ++nt)
                    acc[ct * 2 + nt] = MFMA16(a0, bat[nt], acc[ct * 2 + nt]);
            }
            LGKM0();  // whT reads drained before hp overwrites scratch
            // elu + hp store: sScr[row][cd] (bf16, pitch 136)
#pragma unroll
            for (int ct = 0; ct < 8; ++ct)
#pragma unroll
                for (int nt = 0; nt < 2; ++nt) {
                    f32x4 v = acc[ct * 2 + nt];
#pragma unroll
                    for (int j = 0; j < 4; ++j) {
                        float x = v[j];
                        v[j] = x > 0.f ? x : (__expf(x) - 1.f);
                    }
                    *(ull_a*)&sScr[w][(16 * nt + c) * 136 + 16 * ct + 4 * q] = pack4(v);
                }
            LGKM0();
        } else {
            // GEMM2 (transposed out): goutT[o][n] += W2_h . hp^T
#pragma unroll
            for (int kk = 0; kk < 4; ++kk) {
                bf16x8 bh[2];
#pragma unroll
                for (int nt = 0; nt < 2; ++nt)
                    bh[nt] = *(const bf16x8_a*)&sScr[w][(16 * nt + c) * 136 + 32 * kk + 8 * q];
#pragma unroll
                for (int ot = 0; ot < 8; ++ot) {
                    bf16x8 aw = *(const bf16x8_a*)&sW[(16 * ot + c) * 136 + 32 * kk + 8 * q];
#pragma unroll
                    for (int nt = 0; nt < 2; ++nt) gacc[ot][nt] = MFMA16(aw, bh[nt], gacc[ot][nt]);
                }
            }
            if (h == 3) {  // epilogue: residual + bias + layernorm (per layer)
                LGKM0();
#pragma unroll
                for (int ot = 0; ot < 8; ++ot)
#pragma unroll
                    for (int nt = 0; nt < 2; ++nt)
                        *(ull_a*)&sScr[w][(16 * nt + c) * 136 + 16 * ot + 4 * q] = pack4(gacc[ot][nt]);
                LGKM0();
                const float* ob = out_b + l * 128;
                float sum[2] = {0.f, 0.f}, ssq[2] = {0.f, 0.f};
#pragma unroll
                for (int mt = 0; mt < 2; ++mt)
#pragma unroll
                    for (int kk = 0; kk < 4; ++kk) {
                        bf16x8 g8 = *(const bf16x8_a*)&sScr[w][(16 * mt + c) * 136 + 32 * kk + 8 * q];
                        bf16x8 x8 = xf[mt][kk];
                        const int f0 = 32 * kk + 8 * q;
#pragma unroll
                        for (int j = 0; j < 8; ++j) {
                            float x = bf2f(g8[j]) + bf2f(x8[j]) + ob[f0 + j];
                            sum[mt] += x;
                            ssq[mt] += x * x;
                        }
                    }
                float mu[2], rs[2];
#pragma unroll
                for (int mt = 0; mt < 2; ++mt) {
                    sum[mt] += __shfl_xor(sum[mt], 16);
                    sum[mt] += __shfl_xor(sum[mt], 32);
                    ssq[mt] += __shfl_xor(ssq[mt], 16);
                    ssq[mt] += __shfl_xor(ssq[mt], 32);
                    mu[mt] = sum[mt] * (1.0f / 128.0f);
                    float var = ssq[mt] * (1.0f / 128.0f) - mu[mt] * mu[mt];
                    rs[mt] = rsqrtf(var + 1e-5f);
                }
                const float* lsc = ln_s + l * 128;
                const float* lbi = ln_b + l * 128;
#pragma unroll
                for (int mt = 0; mt < 2; ++mt) {
                    const long row = wrow0 + 16 * mt + c;
#pragma unroll
                    for (int kk = 0; kk < 4; ++kk) {
                        bf16x8 g8 = *(const bf16x8_a*)&sScr[w][(16 * mt + c) * 136 + 32 * kk + 8 * q];
                        bf16x8 x8 = xf[mt][kk];
                        const int f0 = 32 * kk + 8 * q;
                        float y[8];
#pragma unroll
                        for (int j = 0; j < 8; ++j) {
                            float x = bf2f(g8[j]) + bf2f(x8[j]) + ob[f0 + j];
                            y[j] = (x - mu[mt]) * rs[mt] * lsc[f0 + j] + lbi[f0 + j];
                        }
                        if (l == 0) {
                            bf16x8 r;
#pragma unroll
                            for (int j = 0; j < 8; ++j) r[j] = (short)f2bf(y[j]);
                            xf[mt][kk] = r;
                        } else {
                            float4 o0 = {y[0], y[1], y[2], y[3]};
                            float4 o1 = {y[4], y[5], y[6], y[7]};
                            *(float4*)(out + (size_t)row * 128 + f0) = o0;
                            *(float4*)(out + (size_t)row * 128 + f0 + 4) = o1;
                        }
                    }
                }
            }
        }
        __syncthreads();  // all sW reads drained before next chunk's commit
    }
}

extern "C" void kernel_launch(void* const* d_in, const int* in_sizes, int n_in, void* d_out,
                              int out_size, void* d_ws, size_t ws_size, hipStream_t stream) {
    const float* shared_emb = (const float*)d_in[0];
    const float* te = (const float*)d_in[1];
    const float* W_in = (const float*)d_in[2];
    const float* b_in = (const float*)d_in[3];
    const float* W_heads = (const float*)d_in[4];
    const float* a_heads = (const float*)d_in[5];
    const float* out_W = (const float*)d_in[6];
    const float* out_b = (const float*)d_in[7];
    const float* ln_s = (const float*)d_in[8];
    const float* ln_b = (const float*)d_in[9];
    const float* om_i = (const float*)d_in[10];
    const float* om_c = (const float*)d_in[11];
    const int* adj = (const int*)d_in[12];
    const int* et = (const int*)d_in[13];
    float* out = (float*)d_out;

    unsigned short* wsW1 = (unsigned short*)d_ws;          // [2][4][128][128] bf16
    unsigned short* wsW2 = wsW1 + 131072;                  // [2][128][512] bf16
    unsigned short* wsWsd = wsW2 + 131072;                 // [2][16][128] bf16
    float* wsHt = (float*)((char*)d_ws + 532480);          // [8][128] f32
    float* wsEw = wsHt + 1024;                             // [64] f32
    // total ws need: 536,832 bytes

    float* eout = out + (out_size - 64);  // ew output tail

    gat_prep<<<1045, 256, 0, stream>>>(te, W_in, b_in, W_heads, a_heads, om_i, om_c, adj, et,
                                       out_W, wsW1, wsW2, wsWsd, wsHt, wsEw, eout);

    const int B = in_sizes[0] / 128;       // 16384
    const int grid = (B * 8) / 256;        // 512 blocks, 256 rows each
    gat_main<<<grid, 512, 0, stream>>>(shared_emb, out_b, ln_s, ln_b, wsW1, wsW2, wsWsd, wsHt,
                                       wsEw, out);
}